// Round 1
// baseline (2316.546 us; speedup 1.0000x reference)
//
#include <hip/hip_runtime.h>
#include <hip/hip_bf16.h>

#define NN 50000
#define NE 800000

typedef __bf16 bf16_t;
typedef bf16_t bf16x4 __attribute__((ext_vector_type(4)));
typedef bf16_t bf16x8 __attribute__((ext_vector_type(8)));
typedef float f32x4 __attribute__((ext_vector_type(4)));

// Load an 8-element MFMA fragment: elements {p[0..3], p[16..19]}
// (the two 4-element k-halves of gfx950 16x16x32 A/B layout).
__device__ __forceinline__ bf16x8 load_frag(const bf16_t* p) {
    bf16x4 lo = *(const bf16x4*)p;
    bf16x4 hi = *(const bf16x4*)(p + 16);
    bf16x8 f;
    f[0] = lo[0]; f[1] = lo[1]; f[2] = lo[2]; f[3] = lo[3];
    f[4] = hi[0]; f[5] = hi[1]; f[6] = hi[2]; f[7] = hi[3];
    return f;
}

// h[n][j] = x[n][:3] @ in_w[:,j] + in_b[j], stored bf16
__global__ void k_input(const float* __restrict__ x, const float* __restrict__ w,
                        const float* __restrict__ b, bf16_t* __restrict__ h) {
    int gid = blockIdx.x * blockDim.x + threadIdx.x;
    if (gid >= NN * 64) return;
    int n = gid >> 6, j = gid & 63;
    float a = b[j];
    a += x[n * 3 + 0] * w[0 * 64 + j];
    a += x[n * 3 + 1] * w[1 * 64 + j];
    a += x[n * 3 + 2] * w[2 * 64 + j];
    h[gid] = (bf16_t)a;
}

// Transpose + bf16-convert all layer weights:
//  w1t[l][hid][k]  = msg_w1[l][k][hid]   (64x128 per layer)
//  w2t[l][out][k]  = msg_w2[l][k][out]   (64x64)
//  u1t/u2t same from upd_w1/upd_w2
__global__ void k_prep(const float* __restrict__ mw1, const float* __restrict__ mw2,
                       const float* __restrict__ uw1, const float* __restrict__ uw2,
                       bf16_t* __restrict__ w1t, bf16_t* __restrict__ w2t,
                       bf16_t* __restrict__ u1t, bf16_t* __restrict__ u2t) {
    int gid = blockIdx.x * blockDim.x + threadIdx.x;
    if (gid < 3 * 64 * 128) {
        int l = gid / 8192, r = gid % 8192, hid = r >> 7, k = r & 127;
        w1t[gid] = (bf16_t)mw1[l * 8192 + k * 64 + hid];
        u1t[gid] = (bf16_t)uw1[l * 8192 + k * 64 + hid];
    }
    if (gid < 3 * 64 * 64) {
        int l = gid / 4096, r = gid % 4096, o = r >> 6, k = r & 63;
        w2t[gid] = (bf16_t)mw2[l * 4096 + k * 64 + o];
        u2t[gid] = (bf16_t)uw2[l * 4096 + k * 64 + o];
    }
}

// Edge-message MLP + scatter-add.  Per wave-tile of 16 edges:
//   C1 = W1^T(64x128) @ msg_in^T(128x16)  -> hidden^T  (4 MFMA n-tiles x 4 k-steps)
//   C2 = W2^T(64x64)  @ hidden^T(64x16)   -> m^T       (4 x 2)
// Swapped operands make lane-local acc1 registers exactly the B-fragments of
// GEMM2 (k = 4g + (j&3) + 16*(j>>2)): no LDS bounce.
__global__ __launch_bounds__(256, 2)
void k_message(const bf16_t* __restrict__ h, const int* __restrict__ ei,
               const bf16_t* __restrict__ w1t, const bf16_t* __restrict__ w2t,
               const float* __restrict__ b1, const float* __restrict__ b2,
               float* __restrict__ agg) {
    const int lane = threadIdx.x & 63;
    const int g = lane >> 4;      // k-group 0..3
    const int m16 = lane & 15;    // edge slot / weight row within tile
    const int wid = (blockIdx.x * blockDim.x + threadIdx.x) >> 6;
    const int nw = (gridDim.x * blockDim.x) >> 6;

    bf16x8 w1f[4][4];             // [k-step][n-tile]
    #pragma unroll
    for (int s = 0; s < 4; ++s)
        #pragma unroll
        for (int nt = 0; nt < 4; ++nt)
            w1f[s][nt] = load_frag(w1t + (16 * nt + m16) * 128 + 32 * s + 4 * g);
    bf16x8 w2f[2][4];
    #pragma unroll
    for (int s = 0; s < 2; ++s)
        #pragma unroll
        for (int nt = 0; nt < 4; ++nt)
            w2f[s][nt] = load_frag(w2t + (16 * nt + m16) * 64 + 32 * s + 4 * g);
    float b1f[4][4], b2f[4][4];   // bias for acc row hid/out = 16*nt + 4*g + r
    #pragma unroll
    for (int nt = 0; nt < 4; ++nt)
        #pragma unroll
        for (int r = 0; r < 4; ++r) {
            b1f[nt][r] = b1[16 * nt + 4 * g + r];
            b2f[nt][r] = b2[16 * nt + 4 * g + r];
        }

    const int ntiles = NE / 16;
    for (int t = wid; t < ntiles; t += nw) {
        const int e = t * 16 + m16;
        const int ridx = ei[e];
        const int cidx = ei[NE + e];
        const bf16_t* hr = h + ridx * 64 + 4 * g;
        const bf16_t* hc = h + cidx * 64 + 4 * g;
        bf16x8 bfr[4];
        bfr[0] = load_frag(hr);
        bfr[1] = load_frag(hr + 32);
        bfr[2] = load_frag(hc);
        bfr[3] = load_frag(hc + 32);

        f32x4 acc1[4];
        #pragma unroll
        for (int nt = 0; nt < 4; ++nt) acc1[nt] = (f32x4){0.f, 0.f, 0.f, 0.f};
        #pragma unroll
        for (int s = 0; s < 4; ++s)
            #pragma unroll
            for (int nt = 0; nt < 4; ++nt)
                acc1[nt] = __builtin_amdgcn_mfma_f32_16x16x32_bf16(w1f[s][nt], bfr[s], acc1[nt], 0, 0, 0);

        bf16x8 hb[2];
        #pragma unroll
        for (int s = 0; s < 2; ++s) {
            bf16x8 f;
            #pragma unroll
            for (int half = 0; half < 2; ++half) {
                const int nt = 2 * s + half;
                #pragma unroll
                for (int r = 0; r < 4; ++r) {
                    float v = acc1[nt][r] + b1f[nt][r];
                    v = v > 0.f ? v : 0.f;
                    f[4 * half + r] = (bf16_t)v;
                }
            }
            hb[s] = f;
        }

        f32x4 acc2[4];
        #pragma unroll
        for (int nt = 0; nt < 4; ++nt) acc2[nt] = (f32x4){0.f, 0.f, 0.f, 0.f};
        #pragma unroll
        for (int s = 0; s < 2; ++s)
            #pragma unroll
            for (int nt = 0; nt < 4; ++nt)
                acc2[nt] = __builtin_amdgcn_mfma_f32_16x16x32_bf16(w2f[s][nt], hb[s], acc2[nt], 0, 0, 0);

        float* ar = agg + cidx * 64 + 4 * g;
        #pragma unroll
        for (int nt = 0; nt < 4; ++nt)
            #pragma unroll
            for (int r = 0; r < 4; ++r)
                unsafeAtomicAdd(ar + 16 * nt + r, acc2[nt][r] + b2f[nt][r]);
    }
}

// Node-update MLP: upd_in = [h[n], agg[n]] -> relu(relu(.W1+b1).W2+b2) -> h_new (bf16)
__global__ __launch_bounds__(256, 2)
void k_update(const bf16_t* __restrict__ h, const float* __restrict__ agg,
              const bf16_t* __restrict__ u1t, const bf16_t* __restrict__ u2t,
              const float* __restrict__ b1, const float* __restrict__ b2,
              bf16_t* __restrict__ hn) {
    const int lane = threadIdx.x & 63;
    const int g = lane >> 4;
    const int m16 = lane & 15;
    const int wid = (blockIdx.x * blockDim.x + threadIdx.x) >> 6;
    const int nw = (gridDim.x * blockDim.x) >> 6;

    bf16x8 w1f[4][4];
    #pragma unroll
    for (int s = 0; s < 4; ++s)
        #pragma unroll
        for (int nt = 0; nt < 4; ++nt)
            w1f[s][nt] = load_frag(u1t + (16 * nt + m16) * 128 + 32 * s + 4 * g);
    bf16x8 w2f[2][4];
    #pragma unroll
    for (int s = 0; s < 2; ++s)
        #pragma unroll
        for (int nt = 0; nt < 4; ++nt)
            w2f[s][nt] = load_frag(u2t + (16 * nt + m16) * 64 + 32 * s + 4 * g);
    float b1f[4][4], b2f[4][4];
    #pragma unroll
    for (int nt = 0; nt < 4; ++nt)
        #pragma unroll
        for (int r = 0; r < 4; ++r) {
            b1f[nt][r] = b1[16 * nt + 4 * g + r];
            b2f[nt][r] = b2[16 * nt + 4 * g + r];
        }

    const int ntiles = NN / 16;
    for (int t = wid; t < ntiles; t += nw) {
        const int node = t * 16 + m16;
        const bf16_t* hp = h + node * 64 + 4 * g;
        bf16x8 bfr[4];
        bfr[0] = load_frag(hp);
        bfr[1] = load_frag(hp + 32);
        const float* ap = agg + node * 64 + 4 * g;
        #pragma unroll
        for (int s = 0; s < 2; ++s) {
            f32x4 lo = *(const f32x4*)(ap + 32 * s);
            f32x4 hi = *(const f32x4*)(ap + 32 * s + 16);
            bf16x8 f;
            #pragma unroll
            for (int r = 0; r < 4; ++r) {
                f[r] = (bf16_t)lo[r];
                f[4 + r] = (bf16_t)hi[r];
            }
            bfr[2 + s] = f;
        }

        f32x4 acc1[4];
        #pragma unroll
        for (int nt = 0; nt < 4; ++nt) acc1[nt] = (f32x4){0.f, 0.f, 0.f, 0.f};
        #pragma unroll
        for (int s = 0; s < 4; ++s)
            #pragma unroll
            for (int nt = 0; nt < 4; ++nt)
                acc1[nt] = __builtin_amdgcn_mfma_f32_16x16x32_bf16(w1f[s][nt], bfr[s], acc1[nt], 0, 0, 0);

        bf16x8 hb[2];
        #pragma unroll
        for (int s = 0; s < 2; ++s) {
            bf16x8 f;
            #pragma unroll
            for (int half = 0; half < 2; ++half) {
                const int nt = 2 * s + half;
                #pragma unroll
                for (int r = 0; r < 4; ++r) {
                    float v = acc1[nt][r] + b1f[nt][r];
                    v = v > 0.f ? v : 0.f;
                    f[4 * half + r] = (bf16_t)v;
                }
            }
            hb[s] = f;
        }

        f32x4 acc2[4];
        #pragma unroll
        for (int nt = 0; nt < 4; ++nt) acc2[nt] = (f32x4){0.f, 0.f, 0.f, 0.f};
        #pragma unroll
        for (int s = 0; s < 2; ++s)
            #pragma unroll
            for (int nt = 0; nt < 4; ++nt)
                acc2[nt] = __builtin_amdgcn_mfma_f32_16x16x32_bf16(w2f[s][nt], hb[s], acc2[nt], 0, 0, 0);

        bf16_t* hr = hn + node * 64 + 4 * g;
        #pragma unroll
        for (int nt = 0; nt < 4; ++nt)
            #pragma unroll
            for (int r = 0; r < 4; ++r) {
                float v = acc2[nt][r] + b2f[nt][r];
                hr[16 * nt + r] = (bf16_t)(v > 0.f ? v : 0.f);
            }
    }
}

// out[n][j] = h[n][:] @ out_w[:,j] + out_b[j]  (fp32)
__global__ void k_out(const bf16_t* __restrict__ h, const float* __restrict__ w,
                      const float* __restrict__ b, float* __restrict__ out) {
    int gid = blockIdx.x * blockDim.x + threadIdx.x;
    if (gid >= NN * 128) return;
    int n = gid >> 7, j = gid & 127;
    float a = b[j];
    const bf16_t* hr = h + n * 64;
    #pragma unroll
    for (int kk = 0; kk < 8; ++kk) {
        bf16x8 hv = *(const bf16x8*)(hr + kk * 8);
        #pragma unroll
        for (int r = 0; r < 8; ++r)
            a += (float)hv[r] * w[(kk * 8 + r) * 128 + j];
    }
    out[gid] = a;
}

extern "C" void kernel_launch(void* const* d_in, const int* in_sizes, int n_in,
                              void* d_out, int out_size, void* d_ws, size_t ws_size,
                              hipStream_t stream) {
    const float* x      = (const float*)d_in[0];
    const int*   ei     = (const int*)d_in[1];
    const float* in_w   = (const float*)d_in[2];
    const float* in_b   = (const float*)d_in[3];
    const float* msg_w1 = (const float*)d_in[4];
    const float* msg_b1 = (const float*)d_in[5];
    const float* msg_w2 = (const float*)d_in[6];
    const float* msg_b2 = (const float*)d_in[7];
    const float* upd_w1 = (const float*)d_in[8];
    const float* upd_b1 = (const float*)d_in[9];
    const float* upd_w2 = (const float*)d_in[10];
    const float* upd_b2 = (const float*)d_in[11];
    const float* out_w  = (const float*)d_in[12];
    const float* out_b  = (const float*)d_in[13];
    float* out = (float*)d_out;

    char* ws = (char*)d_ws;
    bf16_t* h_a = (bf16_t*)(ws);                        // 6.4 MB
    bf16_t* h_b = (bf16_t*)(ws + 6400000);              // 6.4 MB
    float*  agg = (float*)(ws + 12800000);              // 12.8 MB
    bf16_t* w1t = (bf16_t*)(ws + 25600000);             // 48 KB
    bf16_t* w2t = (bf16_t*)(ws + 25600000 + 49152);     // 24 KB
    bf16_t* u1t = (bf16_t*)(ws + 25600000 + 73728);     // 48 KB
    bf16_t* u2t = (bf16_t*)(ws + 25600000 + 122880);    // 24 KB

    k_prep<<<96, 256, 0, stream>>>(msg_w1, msg_w2, upd_w1, upd_w2, w1t, w2t, u1t, u2t);
    k_input<<<(NN * 64 + 255) / 256, 256, 0, stream>>>(x, in_w, in_b, h_a);

    bf16_t* hc = h_a;
    bf16_t* hn = h_b;
    for (int l = 0; l < 3; ++l) {
        hipMemsetAsync(agg, 0, NN * 64 * sizeof(float), stream);
        k_message<<<1024, 256, 0, stream>>>(hc, ei, w1t + l * 8192, w2t + l * 4096,
                                            msg_b1 + l * 64, msg_b2 + l * 64, agg);
        k_update<<<256, 256, 0, stream>>>(hc, agg, u1t + l * 8192, u2t + l * 4096,
                                          upd_b1 + l * 64, upd_b2 + l * 64, hn);
        bf16_t* tmp = hc; hc = hn; hn = tmp;
    }
    k_out<<<(NN * 128 + 255) / 256, 256, 0, stream>>>(hc, out_w, out_b, out);
}

// Round 3
// 632.313 us; speedup vs baseline: 3.6636x; 3.6636x over previous
//
#include <hip/hip_runtime.h>
#include <hip/hip_bf16.h>

#define NN 50000
#define NE 800000

typedef __bf16 bf16_t;
typedef bf16_t bf16x4 __attribute__((ext_vector_type(4)));
typedef bf16_t bf16x8 __attribute__((ext_vector_type(8)));
typedef float f32x4 __attribute__((ext_vector_type(4)));

// 8-element MFMA A/B fragment: {p[0..3], p[16..19]} (two k-halves of 16x16x32).
__device__ __forceinline__ bf16x8 load_frag(const bf16_t* p) {
    bf16x4 lo = *(const bf16x4*)p;
    bf16x4 hi = *(const bf16x4*)(p + 16);
    bf16x8 f;
    f[0] = lo[0]; f[1] = lo[1]; f[2] = lo[2]; f[3] = lo[3];
    f[4] = hi[0]; f[5] = hi[1]; f[6] = hi[2]; f[7] = hi[3];
    return f;
}

// ---------------- input projection: h = x @ in_w + in_b (bf16) ----------------
__global__ void k_input(const float* __restrict__ x, const float* __restrict__ w,
                        const float* __restrict__ b, bf16_t* __restrict__ h) {
    int gid = blockIdx.x * blockDim.x + threadIdx.x;
    if (gid >= NN * 64) return;
    int n = gid >> 6, j = gid & 63;
    float a = b[j];
    a += x[n * 3 + 0] * w[0 * 64 + j];
    a += x[n * 3 + 1] * w[1 * 64 + j];
    a += x[n * 3 + 2] * w[2 * 64 + j];
    h[gid] = (bf16_t)a;
}

// ---------------- weight prep ----------------
// w1t[l][hid][k]=msg_w1[l][k][hid] (64x128); u1t[l][hid][k]=upd_w1[l][k][hid], k<64 (top);
// u2t[l][o][k]=upd_w2[l][k][o] (64x64)
__global__ void k_prep(const float* __restrict__ mw1, const float* __restrict__ uw1,
                       const float* __restrict__ uw2,
                       bf16_t* __restrict__ w1t, bf16_t* __restrict__ u1t,
                       bf16_t* __restrict__ u2t) {
    int gid = blockIdx.x * blockDim.x + threadIdx.x;
    if (gid < 3 * 64 * 128) {
        int l = gid / 8192, r = gid % 8192, hid = r >> 7, k = r & 127;
        w1t[gid] = (bf16_t)mw1[l * 8192 + k * 64 + hid];
    }
    if (gid < 3 * 64 * 64) {
        int l = gid / 4096, r = gid % 4096, hid = r >> 6, k = r & 63;
        u1t[gid] = (bf16_t)uw1[l * 8192 + k * 64 + hid];
        u2t[gid] = (bf16_t)uw2[l * 4096 + k * 64 + hid]; // o==hid role here
    }
}

// W2''^T[l][hid][k] = sum_j msg_w2[l][k][j] * upd_w1[l][64+j][hid]  (bf16)
// cvec[l][hid]     = sum_j msg_b2[l][j]    * upd_w1[l][64+j][hid]  (f32)
__global__ void k_prep2(const float* __restrict__ mw2, const float* __restrict__ mb2,
                        const float* __restrict__ uw1,
                        bf16_t* __restrict__ w2u, float* __restrict__ cvec) {
    int gid = blockIdx.x * blockDim.x + threadIdx.x;
    if (gid < 3 * 64 * 64) {
        int l = gid / 4096, r = gid % 4096, hid = r >> 6, k = r & 63;
        float s = 0.f;
        for (int j = 0; j < 64; ++j)
            s += mw2[l * 4096 + k * 64 + j] * uw1[l * 8192 + (64 + j) * 64 + hid];
        w2u[l * 4096 + hid * 64 + k] = (bf16_t)s;
    }
    if (gid < 3 * 64) {
        int l = gid / 64, hid = gid % 64;
        float s = 0.f;
        for (int j = 0; j < 64; ++j)
            s += mb2[l * 64 + j] * uw1[l * 8192 + (64 + j) * 64 + hid];
        cvec[gid] = s;
    }
}

// ---------------- counting sort of edges by destination ----------------
__global__ void k_hist(const int* __restrict__ ei, int* __restrict__ deg) {
    int gid = blockIdx.x * blockDim.x + threadIdx.x;
    if (gid < NE) atomicAdd(&deg[ei[NE + gid]], 1);
}

#define SCAN_BLKS 196
__global__ void k_scan1(const int* __restrict__ deg, int* __restrict__ tscan,
                        int* __restrict__ part) {
    __shared__ int lds[256];
    int tid = threadIdx.x;
    int gid = blockIdx.x * 256 + tid;
    int v = (gid < NN) ? deg[gid] : 0;
    lds[tid] = v;
    __syncthreads();
    for (int off = 1; off < 256; off <<= 1) {
        int t = (tid >= off) ? lds[tid - off] : 0;
        __syncthreads();
        lds[tid] += t;
        __syncthreads();
    }
    if (gid < NN) tscan[gid] = lds[tid] - v;       // exclusive within block
    if (tid == 255) part[blockIdx.x] = lds[255];   // block total
}

__global__ void k_scan2(const int* __restrict__ part, int* __restrict__ pscan) {
    __shared__ int lds[256];
    int tid = threadIdx.x;
    int v = (tid < SCAN_BLKS) ? part[tid] : 0;
    lds[tid] = v;
    __syncthreads();
    for (int off = 1; off < 256; off <<= 1) {
        int t = (tid >= off) ? lds[tid - off] : 0;
        __syncthreads();
        lds[tid] += t;
        __syncthreads();
    }
    pscan[tid] = lds[tid] - v;                     // exclusive
}

__global__ void k_scan3(const int* __restrict__ tscan, const int* __restrict__ pscan,
                        int* __restrict__ offs, int* __restrict__ cursor) {
    int gid = blockIdx.x * blockDim.x + threadIdx.x;
    if (gid < NN) {
        int o = tscan[gid] + pscan[gid >> 8];
        offs[gid] = o;
        cursor[gid] = o;
    }
    if (gid == 0) offs[NN] = NE;
}

__global__ void k_scatter(const int* __restrict__ ei, int* __restrict__ cursor,
                          int* __restrict__ ssrc) {
    int gid = blockIdx.x * blockDim.x + threadIdx.x;
    if (gid < NE) {
        int c = ei[NE + gid];
        int pos = atomicAdd(&cursor[c], 1);
        ssrc[pos] = ei[gid];
    }
}

// ---------------- per-layer: P = h@W1top, Q = h@W1bot + b1 (MFMA, swapped) ----------------
__global__ void k_pq(const bf16_t* __restrict__ h, const bf16_t* __restrict__ w1t,
                     const float* __restrict__ b1,
                     bf16_t* __restrict__ P, bf16_t* __restrict__ Q) {
    const int lane = threadIdx.x & 63;
    const int g = lane >> 4;
    const int m16 = lane & 15;
    const int wid = (blockIdx.x * blockDim.x + threadIdx.x) >> 6;
    const int nw = (gridDim.x * blockDim.x) >> 6;

    bf16x8 wtop[2][4], wbot[2][4];
    #pragma unroll
    for (int s = 0; s < 2; ++s)
        #pragma unroll
        for (int nt = 0; nt < 4; ++nt) {
            wtop[s][nt] = load_frag(w1t + (16 * nt + m16) * 128 + 32 * s + 4 * g);
            wbot[s][nt] = load_frag(w1t + (16 * nt + m16) * 128 + 64 + 32 * s + 4 * g);
        }
    float b1f[4][4];
    #pragma unroll
    for (int nt = 0; nt < 4; ++nt)
        #pragma unroll
        for (int r = 0; r < 4; ++r) b1f[nt][r] = b1[16 * nt + 4 * g + r];

    const int ntiles = NN / 16;
    for (int t = wid; t < ntiles; t += nw) {
        const int node = t * 16 + m16;
        const bf16_t* hp = h + node * 64 + 4 * g;
        bf16x8 hfr[2];
        hfr[0] = load_frag(hp);
        hfr[1] = load_frag(hp + 32);

        f32x4 accP[4], accQ[4];
        #pragma unroll
        for (int nt = 0; nt < 4; ++nt) {
            accP[nt] = (f32x4){0.f, 0.f, 0.f, 0.f};
            accQ[nt] = (f32x4){0.f, 0.f, 0.f, 0.f};
        }
        #pragma unroll
        for (int s = 0; s < 2; ++s)
            #pragma unroll
            for (int nt = 0; nt < 4; ++nt) {
                accP[nt] = __builtin_amdgcn_mfma_f32_16x16x32_bf16(wtop[s][nt], hfr[s], accP[nt], 0, 0, 0);
                accQ[nt] = __builtin_amdgcn_mfma_f32_16x16x32_bf16(wbot[s][nt], hfr[s], accQ[nt], 0, 0, 0);
            }
        #pragma unroll
        for (int nt = 0; nt < 4; ++nt) {
            bf16x4 vp, vq;
            #pragma unroll
            for (int r = 0; r < 4; ++r) {
                vp[r] = (bf16_t)accP[nt][r];
                vq[r] = (bf16_t)(accQ[nt][r] + b1f[nt][r]);
            }
            *(bf16x4*)(P + node * 64 + 16 * nt + 4 * g) = vp;
            *(bf16x4*)(Q + node * 64 + 16 * nt + 4 * g) = vq;
        }
    }
}

// ---------------- per-layer edge phase: S[n] = sum_{e->n} relu(P[src_e] + Q[n]) ----------------
__global__ void k_edge(const bf16_t* __restrict__ P, const bf16_t* __restrict__ Q,
                       const int* __restrict__ ssrc, const int* __restrict__ offs,
                       bf16_t* __restrict__ S) {
    int gid = blockIdx.x * blockDim.x + threadIdx.x;
    int node = gid >> 6, f = gid & 63;
    if (node >= NN) return;
    float q = (float)Q[node * 64 + f];
    float a = 0.f;
    int beg = offs[node], end = offs[node + 1];
    for (int p = beg; p < end; ++p) {
        int s = ssrc[p];
        float v = (float)P[s * 64 + f] + q;
        a += v > 0.f ? v : 0.f;
    }
    S[node * 64 + f] = (bf16_t)a;
}

// ---------------- per-layer fused update ----------------
// pre1 = h@U1top + S@W2'' + deg*c + ub1; h_new = relu(relu(pre1)@U2 + ub2)
__global__ void k_upd(const bf16_t* __restrict__ h, const bf16_t* __restrict__ S,
                      const int* __restrict__ deg,
                      const bf16_t* __restrict__ u1t, const bf16_t* __restrict__ w2u,
                      const bf16_t* __restrict__ u2t,
                      const float* __restrict__ ub1, const float* __restrict__ cvec,
                      const float* __restrict__ ub2, bf16_t* __restrict__ hn) {
    const int lane = threadIdx.x & 63;
    const int g = lane >> 4;
    const int m16 = lane & 15;
    const int wid = (blockIdx.x * blockDim.x + threadIdx.x) >> 6;
    const int nw = (gridDim.x * blockDim.x) >> 6;

    bf16x8 u1f[2][4], w2f[2][4], u2f[2][4];
    #pragma unroll
    for (int s = 0; s < 2; ++s)
        #pragma unroll
        for (int nt = 0; nt < 4; ++nt) {
            u1f[s][nt] = load_frag(u1t + (16 * nt + m16) * 64 + 32 * s + 4 * g);
            w2f[s][nt] = load_frag(w2u + (16 * nt + m16) * 64 + 32 * s + 4 * g);
            u2f[s][nt] = load_frag(u2t + (16 * nt + m16) * 64 + 32 * s + 4 * g);
        }
    float b1f[4][4], cf[4][4], b2f[4][4];
    #pragma unroll
    for (int nt = 0; nt < 4; ++nt)
        #pragma unroll
        for (int r = 0; r < 4; ++r) {
            b1f[nt][r] = ub1[16 * nt + 4 * g + r];
            cf[nt][r] = cvec[16 * nt + 4 * g + r];
            b2f[nt][r] = ub2[16 * nt + 4 * g + r];
        }

    const int ntiles = NN / 16;
    for (int t = wid; t < ntiles; t += nw) {
        const int node = t * 16 + m16;
        bf16x8 hfr[2], sfr[2];
        hfr[0] = load_frag(h + node * 64 + 4 * g);
        hfr[1] = load_frag(h + node * 64 + 4 * g + 32);
        sfr[0] = load_frag(S + node * 64 + 4 * g);
        sfr[1] = load_frag(S + node * 64 + 4 * g + 32);
        float dv = (float)deg[node];

        f32x4 acc1[4];
        #pragma unroll
        for (int nt = 0; nt < 4; ++nt) acc1[nt] = (f32x4){0.f, 0.f, 0.f, 0.f};
        #pragma unroll
        for (int s = 0; s < 2; ++s)
            #pragma unroll
            for (int nt = 0; nt < 4; ++nt) {
                acc1[nt] = __builtin_amdgcn_mfma_f32_16x16x32_bf16(u1f[s][nt], hfr[s], acc1[nt], 0, 0, 0);
                acc1[nt] = __builtin_amdgcn_mfma_f32_16x16x32_bf16(w2f[s][nt], sfr[s], acc1[nt], 0, 0, 0);
            }

        bf16x8 hb[2];
        #pragma unroll
        for (int s = 0; s < 2; ++s) {
            bf16x8 f;
            #pragma unroll
            for (int half = 0; half < 2; ++half) {
                const int nt = 2 * s + half;
                #pragma unroll
                for (int r = 0; r < 4; ++r) {
                    float v = acc1[nt][r] + b1f[nt][r] + dv * cf[nt][r];
                    v = v > 0.f ? v : 0.f;
                    f[4 * half + r] = (bf16_t)v;
                }
            }
            hb[s] = f;
        }

        f32x4 acc2[4];
        #pragma unroll
        for (int nt = 0; nt < 4; ++nt) acc2[nt] = (f32x4){0.f, 0.f, 0.f, 0.f};
        #pragma unroll
        for (int s = 0; s < 2; ++s)
            #pragma unroll
            for (int nt = 0; nt < 4; ++nt)
                acc2[nt] = __builtin_amdgcn_mfma_f32_16x16x32_bf16(u2f[s][nt], hb[s], acc2[nt], 0, 0, 0);

        #pragma unroll
        for (int nt = 0; nt < 4; ++nt) {
            bf16x4 v4;
            #pragma unroll
            for (int r = 0; r < 4; ++r) {
                float v = acc2[nt][r] + b2f[nt][r];
                v4[r] = (bf16_t)(v > 0.f ? v : 0.f);
            }
            *(bf16x4*)(hn + node * 64 + 16 * nt + 4 * g) = v4;
        }
    }
}

// ---------------- output projection ----------------
__global__ void k_out(const bf16_t* __restrict__ h, const float* __restrict__ w,
                      const float* __restrict__ b, float* __restrict__ out) {
    int gid = blockIdx.x * blockDim.x + threadIdx.x;
    if (gid >= NN * 128) return;
    int n = gid >> 7, j = gid & 127;
    float a = b[j];
    const bf16_t* hr = h + n * 64;
    #pragma unroll
    for (int kk = 0; kk < 8; ++kk) {
        bf16x8 hv = *(const bf16x8*)(hr + kk * 8);
        #pragma unroll
        for (int r = 0; r < 8; ++r)
            a += (float)hv[r] * w[(kk * 8 + r) * 128 + j];
    }
    out[gid] = a;
}

extern "C" void kernel_launch(void* const* d_in, const int* in_sizes, int n_in,
                              void* d_out, int out_size, void* d_ws, size_t ws_size,
                              hipStream_t stream) {
    const float* x      = (const float*)d_in[0];
    const int*   ei     = (const int*)d_in[1];
    const float* in_w   = (const float*)d_in[2];
    const float* in_b   = (const float*)d_in[3];
    const float* msg_w1 = (const float*)d_in[4];
    const float* msg_b1 = (const float*)d_in[5];
    const float* msg_w2 = (const float*)d_in[6];
    const float* msg_b2 = (const float*)d_in[7];
    const float* upd_w1 = (const float*)d_in[8];
    const float* upd_b1 = (const float*)d_in[9];
    const float* upd_w2 = (const float*)d_in[10];
    const float* upd_b2 = (const float*)d_in[11];
    const float* out_w  = (const float*)d_in[12];
    const float* out_b  = (const float*)d_in[13];
    float* out = (float*)d_out;

    char* ws = (char*)d_ws;
    bf16_t* h_a   = (bf16_t*)(ws);
    bf16_t* h_b   = (bf16_t*)(ws + 6400000);
    bf16_t* P     = (bf16_t*)(ws + 12800000);
    bf16_t* Q     = (bf16_t*)(ws + 19200000);
    bf16_t* S     = (bf16_t*)(ws + 25600000);
    int*    ssrc  = (int*)   (ws + 32000000);
    int*    deg   = (int*)   (ws + 35200000);
    int*    offs  = (int*)   (ws + 35400000);
    int*    cursor= (int*)   (ws + 35600128);
    int*    tscan = (int*)   (ws + 35800192);
    int*    part  = (int*)   (ws + 36000256);
    int*    pscan = (int*)   (ws + 36001280);
    bf16_t* w1t   = (bf16_t*)(ws + 36002304);
    bf16_t* u1t   = (bf16_t*)(ws + 36051456);
    bf16_t* u2t   = (bf16_t*)(ws + 36076032);
    bf16_t* w2u   = (bf16_t*)(ws + 36100608);
    float*  cvec  = (float*) (ws + 36125184);

    // weight prep + input projection
    k_prep<<<96, 256, 0, stream>>>(msg_w1, upd_w1, upd_w2, w1t, u1t, u2t);
    k_prep2<<<48, 256, 0, stream>>>(msg_w2, msg_b2, upd_w1, w2u, cvec);
    k_input<<<(NN * 64 + 255) / 256, 256, 0, stream>>>(x, in_w, in_b, h_a);

    // counting sort of edges by destination
    hipMemsetAsync(deg, 0, NN * sizeof(int), stream);
    k_hist<<<(NE + 255) / 256, 256, 0, stream>>>(ei, deg);
    k_scan1<<<SCAN_BLKS, 256, 0, stream>>>(deg, tscan, part);
    k_scan2<<<1, 256, 0, stream>>>(part, pscan);
    k_scan3<<<SCAN_BLKS, 256, 0, stream>>>(tscan, pscan, offs, cursor);
    k_scatter<<<(NE + 255) / 256, 256, 0, stream>>>(ei, cursor, ssrc);

    bf16_t* hc = h_a;
    bf16_t* hn = h_b;
    for (int l = 0; l < 3; ++l) {
        k_pq<<<512, 256, 0, stream>>>(hc, w1t + l * 8192, msg_b1 + l * 64, P, Q);
        k_edge<<<(NN * 64 + 255) / 256, 256, 0, stream>>>(P, Q, ssrc, offs, S);
        k_upd<<<512, 256, 0, stream>>>(hc, S, deg, u1t + l * 4096, w2u + l * 4096,
                                       u2t + l * 4096, upd_b1 + l * 64, cvec + l * 64,
                                       upd_b2 + l * 64, hn);
        bf16_t* tmp = hc; hc = hn; hn = tmp;
    }
    k_out<<<(NN * 128 + 255) / 256, 256, 0, stream>>>(hc, out_w, out_b, out);
}

// Round 5
// 424.156 us; speedup vs baseline: 5.4615x; 1.4908x over previous
//
#include <hip/hip_runtime.h>
#include <hip/hip_bf16.h>

#define NN 50000
#define NE 800000

typedef __bf16 bf16_t;
typedef bf16_t bf16x4 __attribute__((ext_vector_type(4)));
typedef bf16_t bf16x8 __attribute__((ext_vector_type(8)));
typedef float f32x4 __attribute__((ext_vector_type(4)));

// 8-element MFMA A/B fragment: {p[0..3], p[16..19]} (two k-halves of 16x16x32).
__device__ __forceinline__ bf16x8 load_frag(const bf16_t* p) {
    bf16x4 lo = *(const bf16x4*)p;
    bf16x4 hi = *(const bf16x4*)(p + 16);
    bf16x8 f;
    f[0] = lo[0]; f[1] = lo[1]; f[2] = lo[2]; f[3] = lo[3];
    f[4] = hi[0]; f[5] = hi[1]; f[6] = hi[2]; f[7] = hi[3];
    return f;
}

// ---------------- input projection: h = x @ in_w + in_b (bf16) ----------------
__global__ void k_input(const float* __restrict__ x, const float* __restrict__ w,
                        const float* __restrict__ b, bf16_t* __restrict__ h) {
    int gid = blockIdx.x * blockDim.x + threadIdx.x;
    if (gid >= NN * 64) return;
    int n = gid >> 6, j = gid & 63;
    float a = b[j];
    a += x[n * 3 + 0] * w[0 * 64 + j];
    a += x[n * 3 + 1] * w[1 * 64 + j];
    a += x[n * 3 + 2] * w[2 * 64 + j];
    h[gid] = (bf16_t)a;
}

// ---------------- weight prep ----------------
// w1t[l][hid][k]=msg_w1[l][k][hid] (64x128); u1t[l][hid][k]=upd_w1[l][k][hid], k<64 (top);
// u2t[l][o][k]=upd_w2[l][k][o] (64x64)
__global__ void k_prep(const float* __restrict__ mw1, const float* __restrict__ uw1,
                       const float* __restrict__ uw2,
                       bf16_t* __restrict__ w1t, bf16_t* __restrict__ u1t,
                       bf16_t* __restrict__ u2t) {
    int gid = blockIdx.x * blockDim.x + threadIdx.x;
    if (gid < 3 * 64 * 128) {
        int l = gid / 8192, r = gid % 8192, hid = r >> 7, k = r & 127;
        w1t[gid] = (bf16_t)mw1[l * 8192 + k * 64 + hid];
    }
    if (gid < 3 * 64 * 64) {
        int l = gid / 4096, r = gid % 4096, hid = r >> 6, k = r & 63;
        u1t[gid] = (bf16_t)uw1[l * 8192 + k * 64 + hid];
        u2t[gid] = (bf16_t)uw2[l * 4096 + k * 64 + hid]; // o==hid role here
    }
}

// W2''^T[l][hid][k] = sum_j msg_w2[l][k][j] * upd_w1[l][64+j][hid]  (bf16)
// cvec[l][hid]     = sum_j msg_b2[l][j]    * upd_w1[l][64+j][hid]  (f32)
__global__ void k_prep2(const float* __restrict__ mw2, const float* __restrict__ mb2,
                        const float* __restrict__ uw1,
                        bf16_t* __restrict__ w2u, float* __restrict__ cvec) {
    int gid = blockIdx.x * blockDim.x + threadIdx.x;
    if (gid < 3 * 64 * 64) {
        int l = gid / 4096, r = gid % 4096, hid = r >> 6, k = r & 63;
        float s = 0.f;
        for (int j = 0; j < 64; ++j)
            s += mw2[l * 4096 + k * 64 + j] * uw1[l * 8192 + (64 + j) * 64 + hid];
        w2u[l * 4096 + hid * 64 + k] = (bf16_t)s;
    }
    if (gid < 3 * 64) {
        int l = gid / 64, hid = gid % 64;
        float s = 0.f;
        for (int j = 0; j < 64; ++j)
            s += mb2[l * 64 + j] * uw1[l * 8192 + (64 + j) * 64 + hid];
        cvec[gid] = s;
    }
}

// out_w split: whi[j][k] = bf16(out_w[k][j]); wlo[j][k] = bf16(out_w[k][j] - whi)
__global__ void k_prep3(const float* __restrict__ ow,
                        bf16_t* __restrict__ whi, bf16_t* __restrict__ wlo) {
    int gid = blockIdx.x * blockDim.x + threadIdx.x;
    if (gid >= 128 * 64) return;
    int j = gid >> 6, k = gid & 63;
    float w = ow[k * 128 + j];
    bf16_t hi = (bf16_t)w;
    whi[gid] = hi;
    wlo[gid] = (bf16_t)(w - (float)hi);
}

// ---------------- counting sort of edges by destination ----------------
__global__ void k_hist(const int* __restrict__ ei, int* __restrict__ deg) {
    int gid = blockIdx.x * blockDim.x + threadIdx.x;
    if (gid < NE) atomicAdd(&deg[ei[NE + gid]], 1);
}

#define SCAN_BLKS 196
__global__ void k_scan1(const int* __restrict__ deg, int* __restrict__ tscan,
                        int* __restrict__ part) {
    __shared__ int lds[256];
    int tid = threadIdx.x;
    int gid = blockIdx.x * 256 + tid;
    int v = (gid < NN) ? deg[gid] : 0;
    lds[tid] = v;
    __syncthreads();
    for (int off = 1; off < 256; off <<= 1) {
        int t = (tid >= off) ? lds[tid - off] : 0;
        __syncthreads();
        lds[tid] += t;
        __syncthreads();
    }
    if (gid < NN) tscan[gid] = lds[tid] - v;       // exclusive within block
    if (tid == 255) part[blockIdx.x] = lds[255];   // block total
}

__global__ void k_scan2(const int* __restrict__ part, int* __restrict__ pscan) {
    __shared__ int lds[256];
    int tid = threadIdx.x;
    int v = (tid < SCAN_BLKS) ? part[tid] : 0;
    lds[tid] = v;
    __syncthreads();
    for (int off = 1; off < 256; off <<= 1) {
        int t = (tid >= off) ? lds[tid - off] : 0;
        __syncthreads();
        lds[tid] += t;
        __syncthreads();
    }
    pscan[tid] = lds[tid] - v;                     // exclusive
}

__global__ void k_scan3(const int* __restrict__ tscan, const int* __restrict__ pscan,
                        int* __restrict__ offs, int* __restrict__ cursor) {
    int gid = blockIdx.x * blockDim.x + threadIdx.x;
    if (gid < NN) {
        int o = tscan[gid] + pscan[gid >> 8];
        offs[gid] = o;
        cursor[gid] = o;
    }
    if (gid == 0) offs[NN] = NE;
}

__global__ void k_scatter(const int* __restrict__ ei, int* __restrict__ cursor,
                          int* __restrict__ ssrc) {
    int gid = blockIdx.x * blockDim.x + threadIdx.x;
    if (gid < NE) {
        int c = ei[NE + gid];
        int pos = atomicAdd(&cursor[c], 1);
        ssrc[pos] = ei[gid];
    }
}

// ---------------- per-layer: P = h@W1top, Q = h@W1bot + b1 (MFMA, swapped) ----------------
__global__ void k_pq(const bf16_t* __restrict__ h, const bf16_t* __restrict__ w1t,
                     const float* __restrict__ b1,
                     bf16_t* __restrict__ P, bf16_t* __restrict__ Q) {
    const int lane = threadIdx.x & 63;
    const int g = lane >> 4;
    const int m16 = lane & 15;
    const int wid = (blockIdx.x * blockDim.x + threadIdx.x) >> 6;
    const int nw = (gridDim.x * blockDim.x) >> 6;

    bf16x8 wtop[2][4], wbot[2][4];
    #pragma unroll
    for (int s = 0; s < 2; ++s)
        #pragma unroll
        for (int nt = 0; nt < 4; ++nt) {
            wtop[s][nt] = load_frag(w1t + (16 * nt + m16) * 128 + 32 * s + 4 * g);
            wbot[s][nt] = load_frag(w1t + (16 * nt + m16) * 128 + 64 + 32 * s + 4 * g);
        }
    float b1f[4][4];
    #pragma unroll
    for (int nt = 0; nt < 4; ++nt)
        #pragma unroll
        for (int r = 0; r < 4; ++r) b1f[nt][r] = b1[16 * nt + 4 * g + r];

    const int ntiles = NN / 16;
    for (int t = wid; t < ntiles; t += nw) {
        const int node = t * 16 + m16;
        const bf16_t* hp = h + node * 64 + 4 * g;
        bf16x8 hfr[2];
        hfr[0] = load_frag(hp);
        hfr[1] = load_frag(hp + 32);

        f32x4 accP[4], accQ[4];
        #pragma unroll
        for (int nt = 0; nt < 4; ++nt) {
            accP[nt] = (f32x4){0.f, 0.f, 0.f, 0.f};
            accQ[nt] = (f32x4){0.f, 0.f, 0.f, 0.f};
        }
        #pragma unroll
        for (int s = 0; s < 2; ++s)
            #pragma unroll
            for (int nt = 0; nt < 4; ++nt) {
                accP[nt] = __builtin_amdgcn_mfma_f32_16x16x32_bf16(wtop[s][nt], hfr[s], accP[nt], 0, 0, 0);
                accQ[nt] = __builtin_amdgcn_mfma_f32_16x16x32_bf16(wbot[s][nt], hfr[s], accQ[nt], 0, 0, 0);
            }
        #pragma unroll
        for (int nt = 0; nt < 4; ++nt) {
            bf16x4 vp, vq;
            #pragma unroll
            for (int r = 0; r < 4; ++r) {
                vp[r] = (bf16_t)accP[nt][r];
                vq[r] = (bf16_t)(accQ[nt][r] + b1f[nt][r]);
            }
            *(bf16x4*)(P + node * 64 + 16 * nt + 4 * g) = vp;
            *(bf16x4*)(Q + node * 64 + 16 * nt + 4 * g) = vq;
        }
    }
}

// ---------------- per-layer edge phase: S[n] = sum_{e->n} relu(P[src_e] + Q[n]) ----------------
// thread = (node, feature-octet): 8 lanes/node, 8 nodes/wave -> 8 independent
// edge streams per wave; unroll x4 -> up to 32 outstanding gathers.
__global__ void k_edge(const bf16_t* __restrict__ P, const bf16_t* __restrict__ Q,
                       const int* __restrict__ ssrc, const int* __restrict__ offs,
                       bf16_t* __restrict__ S) {
    int gid = blockIdx.x * blockDim.x + threadIdx.x;
    int node = gid >> 3, f8 = gid & 7;
    if (node >= NN) return;
    bf16x8 qv = *(const bf16x8*)(Q + node * 64 + f8 * 8);
    float qf[8], a[8];
    #pragma unroll
    for (int r = 0; r < 8; ++r) { qf[r] = (float)qv[r]; a[r] = 0.f; }
    const int beg = offs[node], end = offs[node + 1];
    int p = beg;
    const int n4 = beg + ((end - beg) & ~3);
    for (; p < n4; p += 4) {
        int s0 = ssrc[p], s1 = ssrc[p + 1], s2 = ssrc[p + 2], s3 = ssrc[p + 3];
        bf16x8 v0 = *(const bf16x8*)(P + s0 * 64 + f8 * 8);
        bf16x8 v1 = *(const bf16x8*)(P + s1 * 64 + f8 * 8);
        bf16x8 v2 = *(const bf16x8*)(P + s2 * 64 + f8 * 8);
        bf16x8 v3 = *(const bf16x8*)(P + s3 * 64 + f8 * 8);
        #pragma unroll
        for (int r = 0; r < 8; ++r) {
            float x0 = (float)v0[r] + qf[r];
            float x1 = (float)v1[r] + qf[r];
            float x2 = (float)v2[r] + qf[r];
            float x3 = (float)v3[r] + qf[r];
            a[r] += (x0 > 0.f ? x0 : 0.f) + (x1 > 0.f ? x1 : 0.f)
                  + (x2 > 0.f ? x2 : 0.f) + (x3 > 0.f ? x3 : 0.f);
        }
    }
    for (; p < end; ++p) {
        int s = ssrc[p];
        bf16x8 v = *(const bf16x8*)(P + s * 64 + f8 * 8);
        #pragma unroll
        for (int r = 0; r < 8; ++r) {
            float x = (float)v[r] + qf[r];
            a[r] += x > 0.f ? x : 0.f;
        }
    }
    bf16x8 sv;
    #pragma unroll
    for (int r = 0; r < 8; ++r) sv[r] = (bf16_t)a[r];
    *(bf16x8*)(S + node * 64 + f8 * 8) = sv;
}

// ---------------- per-layer fused update ----------------
// pre1 = h@U1top + S@W2'' + deg*c + ub1; h_new = relu(relu(pre1)@U2 + ub2)
__global__ void k_upd(const bf16_t* __restrict__ h, const bf16_t* __restrict__ S,
                      const int* __restrict__ deg,
                      const bf16_t* __restrict__ u1t, const bf16_t* __restrict__ w2u,
                      const bf16_t* __restrict__ u2t,
                      const float* __restrict__ ub1, const float* __restrict__ cvec,
                      const float* __restrict__ ub2, bf16_t* __restrict__ hn) {
    const int lane = threadIdx.x & 63;
    const int g = lane >> 4;
    const int m16 = lane & 15;
    const int wid = (blockIdx.x * blockDim.x + threadIdx.x) >> 6;
    const int nw = (gridDim.x * blockDim.x) >> 6;

    bf16x8 u1f[2][4], w2f[2][4], u2f[2][4];
    #pragma unroll
    for (int s = 0; s < 2; ++s)
        #pragma unroll
        for (int nt = 0; nt < 4; ++nt) {
            u1f[s][nt] = load_frag(u1t + (16 * nt + m16) * 64 + 32 * s + 4 * g);
            w2f[s][nt] = load_frag(w2u + (16 * nt + m16) * 64 + 32 * s + 4 * g);
            u2f[s][nt] = load_frag(u2t + (16 * nt + m16) * 64 + 32 * s + 4 * g);
        }
    float b1f[4][4], cf[4][4], b2f[4][4];
    #pragma unroll
    for (int nt = 0; nt < 4; ++nt)
        #pragma unroll
        for (int r = 0; r < 4; ++r) {
            b1f[nt][r] = ub1[16 * nt + 4 * g + r];
            cf[nt][r] = cvec[16 * nt + 4 * g + r];
            b2f[nt][r] = ub2[16 * nt + 4 * g + r];
        }

    const int ntiles = NN / 16;
    for (int t = wid; t < ntiles; t += nw) {
        const int node = t * 16 + m16;
        bf16x8 hfr[2], sfr[2];
        hfr[0] = load_frag(h + node * 64 + 4 * g);
        hfr[1] = load_frag(h + node * 64 + 4 * g + 32);
        sfr[0] = load_frag(S + node * 64 + 4 * g);
        sfr[1] = load_frag(S + node * 64 + 4 * g + 32);
        float dv = (float)deg[node];

        f32x4 acc1[4];
        #pragma unroll
        for (int nt = 0; nt < 4; ++nt) acc1[nt] = (f32x4){0.f, 0.f, 0.f, 0.f};
        #pragma unroll
        for (int s = 0; s < 2; ++s)
            #pragma unroll
            for (int nt = 0; nt < 4; ++nt) {
                acc1[nt] = __builtin_amdgcn_mfma_f32_16x16x32_bf16(u1f[s][nt], hfr[s], acc1[nt], 0, 0, 0);
                acc1[nt] = __builtin_amdgcn_mfma_f32_16x16x32_bf16(w2f[s][nt], sfr[s], acc1[nt], 0, 0, 0);
            }

        bf16x8 hb[2];
        #pragma unroll
        for (int s = 0; s < 2; ++s) {
            bf16x8 f;
            #pragma unroll
            for (int half = 0; half < 2; ++half) {
                const int nt = 2 * s + half;
                #pragma unroll
                for (int r = 0; r < 4; ++r) {
                    float v = acc1[nt][r] + b1f[nt][r] + dv * cf[nt][r];
                    v = v > 0.f ? v : 0.f;
                    f[4 * half + r] = (bf16_t)v;
                }
            }
            hb[s] = f;
        }

        f32x4 acc2[4];
        #pragma unroll
        for (int nt = 0; nt < 4; ++nt) acc2[nt] = (f32x4){0.f, 0.f, 0.f, 0.f};
        #pragma unroll
        for (int s = 0; s < 2; ++s)
            #pragma unroll
            for (int nt = 0; nt < 4; ++nt)
                acc2[nt] = __builtin_amdgcn_mfma_f32_16x16x32_bf16(u2f[s][nt], hb[s], acc2[nt], 0, 0, 0);

        #pragma unroll
        for (int nt = 0; nt < 4; ++nt) {
            bf16x4 v4;
            #pragma unroll
            for (int r = 0; r < 4; ++r) {
                float v = acc2[nt][r] + b2f[nt][r];
                v4[r] = (bf16_t)(v > 0.f ? v : 0.f);
            }
            *(bf16x4*)(hn + node * 64 + 16 * nt + 4 * g) = v4;
        }
    }
}

// ---------------- output projection (MFMA, split hi/lo weights) ----------------
// out^T tile: [whi+wlo]^T(128x64) @ h^T(64x16) per 16-node tile; fp32 out.
__global__ __launch_bounds__(256)
void k_outm(const bf16_t* __restrict__ whi_t, const bf16_t* __restrict__ wlo_t,
            const bf16_t* __restrict__ h, const float* __restrict__ b,
            float* __restrict__ out) {
    const int lane = threadIdx.x & 63;
    const int g = lane >> 4;
    const int m16 = lane & 15;
    const int wid = (blockIdx.x * blockDim.x + threadIdx.x) >> 6;
    const int nw = (gridDim.x * blockDim.x) >> 6;

    bf16x8 whi[2][8], wlo[2][8];
    #pragma unroll
    for (int s = 0; s < 2; ++s)
        #pragma unroll
        for (int nt = 0; nt < 8; ++nt) {
            whi[s][nt] = load_frag(whi_t + (16 * nt + m16) * 64 + 32 * s + 4 * g);
            wlo[s][nt] = load_frag(wlo_t + (16 * nt + m16) * 64 + 32 * s + 4 * g);
        }
    f32x4 bfv[8];
    #pragma unroll
    for (int nt = 0; nt < 8; ++nt)
        #pragma unroll
        for (int r = 0; r < 4; ++r) bfv[nt][r] = b[16 * nt + 4 * g + r];

    const int ntiles = NN / 16;
    for (int t = wid; t < ntiles; t += nw) {
        const int node = t * 16 + m16;
        bf16x8 hfr[2];
        hfr[0] = load_frag(h + node * 64 + 4 * g);
        hfr[1] = load_frag(h + node * 64 + 4 * g + 32);

        f32x4 acc[8];
        #pragma unroll
        for (int nt = 0; nt < 8; ++nt) acc[nt] = (f32x4){0.f, 0.f, 0.f, 0.f};
        #pragma unroll
        for (int s = 0; s < 2; ++s)
            #pragma unroll
            for (int nt = 0; nt < 8; ++nt) {
                acc[nt] = __builtin_amdgcn_mfma_f32_16x16x32_bf16(whi[s][nt], hfr[s], acc[nt], 0, 0, 0);
                acc[nt] = __builtin_amdgcn_mfma_f32_16x16x32_bf16(wlo[s][nt], hfr[s], acc[nt], 0, 0, 0);
            }
        #pragma unroll
        for (int nt = 0; nt < 8; ++nt)
            *(f32x4*)(out + node * 128 + 16 * nt + 4 * g) = acc[nt] + bfv[nt];
    }
}

extern "C" void kernel_launch(void* const* d_in, const int* in_sizes, int n_in,
                              void* d_out, int out_size, void* d_ws, size_t ws_size,
                              hipStream_t stream) {
    const float* x      = (const float*)d_in[0];
    const int*   ei     = (const int*)d_in[1];
    const float* in_w   = (const float*)d_in[2];
    const float* in_b   = (const float*)d_in[3];
    const float* msg_w1 = (const float*)d_in[4];
    const float* msg_b1 = (const float*)d_in[5];
    const float* msg_w2 = (const float*)d_in[6];
    const float* msg_b2 = (const float*)d_in[7];
    const float* upd_w1 = (const float*)d_in[8];
    const float* upd_b1 = (const float*)d_in[9];
    const float* upd_w2 = (const float*)d_in[10];
    const float* upd_b2 = (const float*)d_in[11];
    const float* out_w  = (const float*)d_in[12];
    const float* out_b  = (const float*)d_in[13];
    float* out = (float*)d_out;

    char* ws = (char*)d_ws;
    bf16_t* h_a   = (bf16_t*)(ws);
    bf16_t* h_b   = (bf16_t*)(ws + 6400000);
    bf16_t* P     = (bf16_t*)(ws + 12800000);
    bf16_t* Q     = (bf16_t*)(ws + 19200000);
    bf16_t* S     = (bf16_t*)(ws + 25600000);
    int*    ssrc  = (int*)   (ws + 32000000);
    int*    deg   = (int*)   (ws + 35200000);
    int*    offs  = (int*)   (ws + 35400000);
    int*    cursor= (int*)   (ws + 35600128);
    int*    tscan = (int*)   (ws + 35800192);
    int*    part  = (int*)   (ws + 36000256);
    int*    pscan = (int*)   (ws + 36001280);
    bf16_t* w1t   = (bf16_t*)(ws + 36002304);
    bf16_t* u1t   = (bf16_t*)(ws + 36051456);
    bf16_t* u2t   = (bf16_t*)(ws + 36076032);
    bf16_t* w2u   = (bf16_t*)(ws + 36100608);
    float*  cvec  = (float*) (ws + 36125184);
    bf16_t* whi   = (bf16_t*)(ws + 36126208);   // 16 KB
    bf16_t* wlo   = (bf16_t*)(ws + 36142592);   // 16 KB

    // weight prep + input projection
    k_prep<<<96, 256, 0, stream>>>(msg_w1, upd_w1, upd_w2, w1t, u1t, u2t);
    k_prep2<<<48, 256, 0, stream>>>(msg_w2, msg_b2, upd_w1, w2u, cvec);
    k_prep3<<<32, 256, 0, stream>>>(out_w, whi, wlo);
    k_input<<<(NN * 64 + 255) / 256, 256, 0, stream>>>(x, in_w, in_b, h_a);

    // counting sort of edges by destination
    hipMemsetAsync(deg, 0, NN * sizeof(int), stream);
    k_hist<<<(NE + 255) / 256, 256, 0, stream>>>(ei, deg);
    k_scan1<<<SCAN_BLKS, 256, 0, stream>>>(deg, tscan, part);
    k_scan2<<<1, 256, 0, stream>>>(part, pscan);
    k_scan3<<<SCAN_BLKS, 256, 0, stream>>>(tscan, pscan, offs, cursor);
    k_scatter<<<(NE + 255) / 256, 256, 0, stream>>>(ei, cursor, ssrc);

    bf16_t* hc = h_a;
    bf16_t* hn = h_b;
    for (int l = 0; l < 3; ++l) {
        k_pq<<<512, 256, 0, stream>>>(hc, w1t + l * 8192, msg_b1 + l * 64, P, Q);
        k_edge<<<(NN * 8 + 255) / 256, 256, 0, stream>>>(P, Q, ssrc, offs, S);
        k_upd<<<512, 256, 0, stream>>>(hc, S, deg, u1t + l * 4096, w2u + l * 4096,
                                       u2t + l * 4096, upd_b1 + l * 64, cvec + l * 64,
                                       upd_b2 + l * 64, hn);
        bf16_t* tmp = hc; hc = hn; hn = tmp;
    }
    k_outm<<<640, 256, 0, stream>>>(whi, wlo, hc, out_b, out);
}